// Round 5
// baseline (81.307 us; speedup 1.0000x reference)
//
#include <hip/hip_runtime.h>

// out = relu((x @ B^T) * A^T + bias)  -- rank-1 reassociated form.
// x: [8192, 2048] f32, A: [10000,1] f32, B: [1,2048] f32, bias: [10000] f32
// out: [8192, 10000] f32
//
// Fused, 4 rows per block. Output stores NONTEMPORAL (bypass L2 allocate:
// R3 proved this, 110->69.5us). x loads also nontemporal (read-once stream,
// keep the hot 80KB A/bias set resident in L2). RPB=4 amortizes phase-1
// latency and gives 4 stores per A/bias L2 load in phase 2.

#define BATCH       8192
#define IN_FEATURES 2048
#define N_CLASSES   10000
#define NC4         (N_CLASSES / 4)   // 2500
#define BLOCK       256
#define RPB         4                 // rows per block

typedef float fx4 __attribute__((ext_vector_type(4)));

__global__ __launch_bounds__(BLOCK) void lora_fused4_kernel(
    const float* __restrict__ x,
    const float* __restrict__ A,
    const float* __restrict__ B,
    const float* __restrict__ bias,
    float* __restrict__ out)
{
    const int tid  = threadIdx.x;
    const int row0 = blockIdx.x * RPB;

    // ---- Phase 1: s[r] = dot(x[row0+r,:], B) for r in 0..3 ----
    const fx4* __restrict__ B4 = reinterpret_cast<const fx4*>(B);
    fx4 ba = B4[tid];
    fx4 bb = B4[tid + BLOCK];

    float acc[RPB];
    #pragma unroll
    for (int r = 0; r < RPB; ++r) {
        const fx4* __restrict__ xr = reinterpret_cast<const fx4*>(x + (size_t)(row0 + r) * IN_FEATURES);
        fx4 xa = __builtin_nontemporal_load(&xr[tid]);
        fx4 xb = __builtin_nontemporal_load(&xr[tid + BLOCK]);
        float a = 0.0f;
        a = fmaf(xa.x, ba.x, a);
        a = fmaf(xa.y, ba.y, a);
        a = fmaf(xa.z, ba.z, a);
        a = fmaf(xa.w, ba.w, a);
        a = fmaf(xb.x, bb.x, a);
        a = fmaf(xb.y, bb.y, a);
        a = fmaf(xb.z, bb.z, a);
        a = fmaf(xb.w, bb.w, a);
        acc[r] = a;
    }

    #pragma unroll
    for (int off = 32; off > 0; off >>= 1) {
        #pragma unroll
        for (int r = 0; r < RPB; ++r)
            acc[r] += __shfl_down(acc[r], off, 64);
    }

    __shared__ float wsum[RPB][BLOCK / 64];
    __shared__ float sb[RPB];
    const int lane = tid & 63;
    const int wid  = tid >> 6;
    if (lane == 0) {
        #pragma unroll
        for (int r = 0; r < RPB; ++r) wsum[r][wid] = acc[r];
    }
    __syncthreads();
    if (tid < RPB)
        sb[tid] = wsum[tid][0] + wsum[tid][1] + wsum[tid][2] + wsum[tid][3];
    __syncthreads();

    float s[RPB];
    #pragma unroll
    for (int r = 0; r < RPB; ++r) s[r] = sb[r];

    // ---- Phase 2: out[row0+r, j] = relu(s[r]*A[j] + bias[j]), nontemporal ----
    const fx4* __restrict__ A4  = reinterpret_cast<const fx4*>(A);
    const fx4* __restrict__ bb4 = reinterpret_cast<const fx4*>(bias);
    fx4* __restrict__ o0 = reinterpret_cast<fx4*>(out) + (size_t)row0 * NC4;

    for (int j = tid; j < NC4; j += BLOCK) {
        fx4 a = A4[j];
        fx4 b = bb4[j];
        #pragma unroll
        for (int r = 0; r < RPB; ++r) {
            fx4 v;
            v.x = fmaxf(fmaf(s[r], a.x, b.x), 0.0f);
            v.y = fmaxf(fmaf(s[r], a.y, b.y), 0.0f);
            v.z = fmaxf(fmaf(s[r], a.z, b.z), 0.0f);
            v.w = fmaxf(fmaf(s[r], a.w, b.w), 0.0f);
            __builtin_nontemporal_store(v, &o0[(size_t)r * NC4 + j]);
        }
    }
}

extern "C" void kernel_launch(void* const* d_in, const int* in_sizes, int n_in,
                              void* d_out, int out_size, void* d_ws, size_t ws_size,
                              hipStream_t stream) {
    const float* x    = (const float*)d_in[0];
    const float* A    = (const float*)d_in[1];
    const float* B    = (const float*)d_in[2];
    const float* bias = (const float*)d_in[3];
    float* out        = (float*)d_out;

    lora_fused4_kernel<<<BATCH / RPB, BLOCK, 0, stream>>>(x, A, B, bias, out);
}

// Round 6
// 79.050 us; speedup vs baseline: 1.0286x; 1.0286x over previous
//
#include <hip/hip_runtime.h>

// out = relu((x @ B^T) * A^T + bias)  -- rank-1 reassociated form.
// x: [8192, 2048] f32, A: [10000,1] f32, B: [1,2048] f32, bias: [10000] f32
// out: [8192, 10000] f32
//
// Wave-independent software pipeline. Each wave owns ROWS_PER_WAVE=4
// consecutive rows: consume prefetched x-row from regs -> issue next row's
// loads -> in-wave shuffle reduce (no LDS/barriers, so no vmcnt(0) drains)
// -> nontemporal-store the 40KB output row while the prefetch flies.
// NT stores (R3: 110->69.5us) bypass L2 allocate; x reads hide under stores.

#define BATCH       8192
#define IN_FEATURES 2048
#define N_CLASSES   10000
#define NC4         2500
#define BLOCK       256
#define WPB         4      // waves per block
#define RPW         4      // rows per wave
#define GRID        (BATCH / (WPB * RPW))   // 512

typedef float fx4 __attribute__((ext_vector_type(4)));

__device__ __forceinline__ float dot8(const fx4* xv, const fx4* Bv) {
    float a = 0.0f;
    #pragma unroll
    for (int k = 0; k < 8; ++k) {
        a = fmaf(xv[k].x, Bv[k].x, a);
        a = fmaf(xv[k].y, Bv[k].y, a);
        a = fmaf(xv[k].z, Bv[k].z, a);
        a = fmaf(xv[k].w, Bv[k].w, a);
    }
    return a;
}

__global__ __launch_bounds__(BLOCK) void lora_wavepipe_kernel(
    const float* __restrict__ x,
    const float* __restrict__ A,
    const float* __restrict__ B,
    const float* __restrict__ bias,
    float* __restrict__ out)
{
    const int tid  = threadIdx.x;
    const int lane = tid & 63;
    const int wid  = tid >> 6;
    const int wg   = blockIdx.x * WPB + wid;   // global wave id
    const int row0 = wg * RPW;

    const fx4* __restrict__ B4  = reinterpret_cast<const fx4*>(B);
    const fx4* __restrict__ A4  = reinterpret_cast<const fx4*>(A);
    const fx4* __restrict__ bb4 = reinterpret_cast<const fx4*>(bias);

    // B fragment: lane handles f4 indices lane + 64*k  (8 KB, L2-hot)
    fx4 Bv[8];
    #pragma unroll
    for (int k = 0; k < 8; ++k) Bv[k] = B4[lane + 64 * k];

    // double-buffered x-row fragments (static indexing: r-loop fully unrolled)
    fx4 xbuf[2][8];
    {
        const fx4* __restrict__ xr = reinterpret_cast<const fx4*>(x + (size_t)row0 * IN_FEATURES);
        #pragma unroll
        for (int k = 0; k < 8; ++k) xbuf[0][k] = xr[lane + 64 * k];
    }

    #pragma unroll
    for (int r = 0; r < RPW; ++r) {
        const int cur = r & 1;

        // consume current row (waits on its 8 loads; they were issued a full
        // store-loop ago for r>0)
        float acc = dot8(xbuf[cur], Bv);

        // prefetch next row NOW -- overlaps with reduce + store loop below
        if (r + 1 < RPW) {
            const fx4* __restrict__ xr =
                reinterpret_cast<const fx4*>(x + (size_t)(row0 + r + 1) * IN_FEATURES);
            #pragma unroll
            for (int k = 0; k < 8; ++k) xbuf[cur ^ 1][k] = xr[lane + 64 * k];
        }

        // in-wave reduce + broadcast (no LDS, no barriers)
        #pragma unroll
        for (int off = 32; off > 0; off >>= 1)
            acc += __shfl_down(acc, off, 64);
        const float s = __shfl(acc, 0, 64);

        // stream the output row, nontemporal
        fx4* __restrict__ o = reinterpret_cast<fx4*>(out) + (size_t)(row0 + r) * NC4;
        #pragma unroll 4
        for (int j = lane; j < NC4; j += 64) {
            fx4 a = A4[j];
            fx4 b = bb4[j];
            fx4 v;
            v.x = fmaxf(fmaf(s, a.x, b.x), 0.0f);
            v.y = fmaxf(fmaf(s, a.y, b.y), 0.0f);
            v.z = fmaxf(fmaf(s, a.z, b.z), 0.0f);
            v.w = fmaxf(fmaf(s, a.w, b.w), 0.0f);
            __builtin_nontemporal_store(v, &o[j]);
        }
    }
}

extern "C" void kernel_launch(void* const* d_in, const int* in_sizes, int n_in,
                              void* d_out, int out_size, void* d_ws, size_t ws_size,
                              hipStream_t stream) {
    const float* x    = (const float*)d_in[0];
    const float* A    = (const float*)d_in[1];
    const float* B    = (const float*)d_in[2];
    const float* bias = (const float*)d_in[3];
    float* out        = (float*)d_out;

    lora_wavepipe_kernel<<<GRID, BLOCK, 0, stream>>>(x, A, B, bias, out);
}

// Round 7
// 77.721 us; speedup vs baseline: 1.0461x; 1.0171x over previous
//
#include <hip/hip_runtime.h>

// out = relu((x @ B^T) * A^T + bias)  -- rank-1 reassociated form.
// x: [8192, 2048] f32, A: [10000,1] f32, B: [1,2048] f32, bias: [10000] f32
// out: [8192, 10000] f32
//
// Two-kernel split, each phase at its PURE-stream DRAM rate:
//   K1 (read-bound):  s[row] = dot(x[row,:], B)  -- wave-per-row, no barriers,
//                     NT loads for x (read-once), ~67 MB @ ~6.3 TB/s.
//   K2 (write-bound): out[r,j] = relu(s[r]*A[j]+bias[j]) -- pure NT-store
//                     stream (R3 proved NT stores: +37%), A/bias in regs,
//                     32 rows/block, ~328 MB @ ~7 TB/s (memset rate).
// Serial floor ~58 us vs fused-mixed roofline ~69 us (R3 measured).

#define BATCH       8192
#define IN_FEATURES 2048
#define N_CLASSES   10000
#define NC4         2500   // N_CLASSES/4
#define NF4         512    // IN_FEATURES/4
#define BLOCK       256
#define K2_ROWS     32

typedef float fx4 __attribute__((ext_vector_type(4)));

// ---------------- K1: wave-per-row dot product ----------------
__global__ __launch_bounds__(BLOCK) void lora_dot_wave_kernel(
    const float* __restrict__ x,
    const float* __restrict__ B,
    float* __restrict__ s_out)
{
    const int lane = threadIdx.x & 63;
    const int wid  = threadIdx.x >> 6;
    const int row  = blockIdx.x * 4 + wid;

    const fx4* __restrict__ xr = reinterpret_cast<const fx4*>(x + (size_t)row * IN_FEATURES);
    const fx4* __restrict__ B4 = reinterpret_cast<const fx4*>(B);

    float acc = 0.0f;
    #pragma unroll
    for (int k = 0; k < NF4 / 64; ++k) {          // 8 f4 per lane
        fx4 xv = __builtin_nontemporal_load(&xr[lane + 64 * k]);
        fx4 bv = B4[lane + 64 * k];
        acc = fmaf(xv.x, bv.x, acc);
        acc = fmaf(xv.y, bv.y, acc);
        acc = fmaf(xv.z, bv.z, acc);
        acc = fmaf(xv.w, bv.w, acc);
    }

    #pragma unroll
    for (int off = 32; off > 0; off >>= 1)
        acc += __shfl_down(acc, off, 64);

    if (lane == 0) s_out[row] = acc;
}

// ---------------- K2: pure nontemporal store broadcast ----------------
// grid: (10 column-chunks of 256 f4, 256 row-groups of 32 rows)
__global__ __launch_bounds__(BLOCK) void lora_store_kernel(
    const float* __restrict__ s_vec,
    const float* __restrict__ A,
    const float* __restrict__ bias,
    float* __restrict__ out)
{
    const int tid  = threadIdx.x;
    const int col4 = blockIdx.x * BLOCK + tid;
    const int row0 = blockIdx.y * K2_ROWS;

    __shared__ float s_lds[K2_ROWS];
    if (tid < K2_ROWS) s_lds[tid] = s_vec[row0 + tid];
    __syncthreads();

    if (col4 >= NC4) return;

    const fx4 a = reinterpret_cast<const fx4*>(A)[col4];
    const fx4 b = reinterpret_cast<const fx4*>(bias)[col4];

    fx4* __restrict__ o = reinterpret_cast<fx4*>(out) + (size_t)row0 * NC4 + col4;

    #pragma unroll
    for (int r = 0; r < K2_ROWS; ++r) {
        const float s = s_lds[r];
        fx4 v;
        v.x = fmaxf(fmaf(s, a.x, b.x), 0.0f);
        v.y = fmaxf(fmaf(s, a.y, b.y), 0.0f);
        v.z = fmaxf(fmaf(s, a.z, b.z), 0.0f);
        v.w = fmaxf(fmaf(s, a.w, b.w), 0.0f);
        __builtin_nontemporal_store(v, &o[(size_t)r * NC4]);
    }
}

extern "C" void kernel_launch(void* const* d_in, const int* in_sizes, int n_in,
                              void* d_out, int out_size, void* d_ws, size_t ws_size,
                              hipStream_t stream) {
    const float* x    = (const float*)d_in[0];
    const float* A    = (const float*)d_in[1];
    const float* B    = (const float*)d_in[2];
    const float* bias = (const float*)d_in[3];
    float* out        = (float*)d_out;
    float* s_vec      = (float*)d_ws;   // 8192 floats

    lora_dot_wave_kernel<<<BATCH / 4, BLOCK, 0, stream>>>(x, B, s_vec);

    dim3 grid((NC4 + BLOCK - 1) / BLOCK, BATCH / K2_ROWS);   // (10, 256)
    lora_store_kernel<<<grid, BLOCK, 0, stream>>>(s_vec, A, bias, out);
}